// Round 1
// baseline (77.119 us; speedup 1.0000x reference)
//
#include <hip/hip_runtime.h>
#include <hip/hip_bf16.h>
#include <math.h>

// Problem constants (from reference)
#define B_   64
#define N_   256
#define DV_  2048
#define DP_  8
#define DT_  768
#define DF_  512
// DV+DP = 2056

// Workspace layout (floats):
//   wT : [DF][B]   = 512*64  = 32768   (w[b,f] = gelu(text@Wt+bt)*Wa, transposed)
//   S  : [B][DP]   = 64*8    = 512     (column sums of position)
//   c  : [B]       = 64                (bo . w[b] + ba)
//   v  : [B][2056] = 131584            (v[b,k] = Wo[k,:] . w[b,:])
#define WS_WT 0
#define WS_S  32768
#define WS_C  33280
#define WS_V  33344

// ---------------------------------------------------------------------------
// Kernel A: per-batch query/w, position column-sums S[b], constant c[b].
// grid = B blocks, 256 threads.
// ---------------------------------------------------------------------------
__global__ __launch_bounds__(256) void kA(
    const float* __restrict__ pos,   // [B][N][DP]
    const float* __restrict__ text,  // [B][N][DT]
    const float* __restrict__ Wt,    // [DT][DF]
    const float* __restrict__ bt,    // [DF]
    const float* __restrict__ Wa,    // [DF]
    const float* __restrict__ bo,    // [DF]
    const float* __restrict__ ba,    // [1]
    float* __restrict__ wT,          // [DF][B]
    float* __restrict__ S,           // [B][DP]
    float* __restrict__ c)           // [B]
{
    const int b = blockIdx.x;
    const int t = threadIdx.x;

    __shared__ float tx[DT_];
    __shared__ float sred[32][DP_];
    __shared__ float red[256];

    // stage text[b, 0, :] (768 floats)
    for (int k = t; k < DT_; k += 256)
        tx[k] = text[(size_t)b * N_ * DT_ + k];

    // position column sums: thread (g = t>>3, d = t&7)
    {
        const int d = t & 7, g = t >> 3;
        float s = 0.f;
        for (int i = g; i < N_; i += 32)
            s += pos[(size_t)b * N_ * DP_ + i * DP_ + d];
        sred[g][d] = s;
    }
    __syncthreads();

    if (t < DP_) {
        float s = 0.f;
        #pragma unroll
        for (int g = 0; g < 32; ++g) s += sred[g][t];
        S[b * DP_ + t] = s;
    }

    // query for f = t and f = t + 256
    float a0 = bt[t];
    float a1 = bt[t + 256];
    for (int k = 0; k < DT_; ++k) {
        const float x = tx[k];
        a0 = fmaf(x, Wt[k * DF_ + t],        a0);
        a1 = fmaf(x, Wt[k * DF_ + t + 256],  a1);
    }
    // exact gelu: 0.5*x*(1+erf(x/sqrt(2)))
    const float g0 = 0.5f * a0 * (1.f + erff(a0 * 0.70710678118654752f));
    const float g1 = 0.5f * a1 * (1.f + erff(a1 * 0.70710678118654752f));
    const float w0 = g0 * Wa[t];
    const float w1 = g1 * Wa[t + 256];
    wT[(size_t)t * B_ + b]         = w0;
    wT[(size_t)(t + 256) * B_ + b] = w1;

    // c[b] = ba + sum_f bo[f] * w[b,f]
    red[t] = bo[t] * w0 + bo[t + 256] * w1;
    __syncthreads();
    for (int s2 = 128; s2 > 0; s2 >>= 1) {
        if (t < s2) red[t] += red[t + s2];
        __syncthreads();
    }
    if (t == 0) c[b] = red[0] + ba[0];
}

// ---------------------------------------------------------------------------
// Kernel B: v[b,k] = sum_f Wo[k,f] * w[b,f].  8 k-rows per block (257 blocks).
// thread layout: b = t & 63, q = t >> 6 owns k = k0 + q*2 + {0,1}.
// ---------------------------------------------------------------------------
__global__ __launch_bounds__(256) void kB(
    const float* __restrict__ Wo,    // [2056][DF]
    const float* __restrict__ wT,    // [DF][B]
    float* __restrict__ v)           // [B][2056]
{
    const int t  = threadIdx.x;
    const int k0 = blockIdx.x * 8;

    __shared__ float wo[8 * DF_];    // 16 KB
    {
        const float4* src = (const float4*)(Wo + (size_t)k0 * DF_);
        float4*       dst = (float4*)wo;
        for (int j = t; j < (8 * DF_) / 4; j += 256)
            dst[j] = src[j];
    }
    __syncthreads();

    const int b = t & 63;
    const int q = t >> 6;
    const float* r0 = wo + (q * 2 + 0) * DF_;
    const float* r1 = wo + (q * 2 + 1) * DF_;

    float a0 = 0.f, a1 = 0.f;
    for (int f = 0; f < DF_; ++f) {
        const float wv = wT[f * B_ + b];   // coalesced across lanes
        a0 = fmaf(r0[f], wv, a0);          // LDS broadcast (uniform addr)
        a1 = fmaf(r1[f], wv, a1);
    }
    v[(size_t)b * 2056 + k0 + q * 2 + 0] = a0;
    v[(size_t)b * 2056 + k0 + q * 2 + 1] = a1;
}

// ---------------------------------------------------------------------------
// Kernel C (bulk, HBM-bound): one wave per output element.
// out[b,i] = visual[b,i,:].v1[b] + 257*pos[b,i,:].v2[b] - S[b].v2[b] + c[b]
// grid = B*N/4 blocks of 256 (4 waves); wave w of block handles one row.
// ---------------------------------------------------------------------------
__global__ __launch_bounds__(256) void kC(
    const float* __restrict__ visual, // [B][N][DV]
    const float* __restrict__ pos,    // [B][N][DP]
    const float* __restrict__ v,      // [B][2056]
    const float* __restrict__ S,      // [B][DP]
    const float* __restrict__ c,      // [B]
    float* __restrict__ out)          // [B][N]
{
    const int t    = threadIdx.x;
    const int wave = t >> 6;
    const int lane = t & 63;
    const int blk  = blockIdx.x;          // 4096
    const int b    = blk >> 6;            // 64 i-tiles per b
    const int i    = ((blk & 63) << 2) | wave;

    const float4* vis = (const float4*)(visual + ((size_t)b * N_ + i) * DV_);
    const float4* vb  = (const float4*)(v + (size_t)b * 2056);

    float acc = 0.f;
    #pragma unroll
    for (int j = 0; j < DV_ / (64 * 4); ++j) {   // 8 iterations
        const float4 a = vis[lane + 64 * j];
        const float4 w = vb [lane + 64 * j];
        acc = fmaf(a.x, w.x, acc);
        acc = fmaf(a.y, w.y, acc);
        acc = fmaf(a.z, w.z, acc);
        acc = fmaf(a.w, w.w, acc);
    }
    // wave64 reduce
    #pragma unroll
    for (int off = 32; off > 0; off >>= 1)
        acc += __shfl_down(acc, off, 64);

    if (lane == 0) {
        const float* v2 = v + (size_t)b * 2056 + DV_;
        const float* pr = pos + ((size_t)b * N_ + i) * DP_;
        const float* Sb = S + b * DP_;
        float pd = 0.f, sd = 0.f;
        #pragma unroll
        for (int d = 0; d < DP_; ++d) {
            pd = fmaf(pr[d], v2[d], pd);
            sd = fmaf(Sb[d], v2[d], sd);
        }
        out[(size_t)b * N_ + i] = acc + 257.f * pd - sd + c[b];
    }
}

// ---------------------------------------------------------------------------
extern "C" void kernel_launch(void* const* d_in, const int* in_sizes, int n_in,
                              void* d_out, int out_size, void* d_ws, size_t ws_size,
                              hipStream_t stream) {
    const float* visual   = (const float*)d_in[0];
    const float* position = (const float*)d_in[1];
    const float* text     = (const float*)d_in[2];
    const float* Wt       = (const float*)d_in[3];
    const float* bt       = (const float*)d_in[4];
    const float* Wo       = (const float*)d_in[5];
    const float* bo       = (const float*)d_in[6];
    const float* Wa       = (const float*)d_in[7];
    const float* ba       = (const float*)d_in[8];
    float* out = (float*)d_out;

    float* ws = (float*)d_ws;
    float* wT = ws + WS_WT;
    float* S  = ws + WS_S;
    float* c  = ws + WS_C;
    float* v  = ws + WS_V;

    kA<<<B_, 256, 0, stream>>>(position, text, Wt, bt, Wa, bo, ba, wT, S, c);
    kB<<<(2056 / 8), 256, 0, stream>>>(Wo, wT, v);
    kC<<<(B_ * N_) / 4, 256, 0, stream>>>(visual, position, v, S, c, out);
}

// Round 2
// 55.699 us; speedup vs baseline: 1.3846x; 1.3846x over previous
//
#include <hip/hip_runtime.h>
#include <hip/hip_bf16.h>
#include <math.h>

// Problem constants
#define B_   64
#define N_   256
#define DV_  2048
#define DP_  8
#define DT_  768
#define DF_  512
#define DK_  2056   // DV + DP

// Workspace layout (floats):
#define WS_WT 0        // wT[DF][B]  = 32768
#define WS_S  32768    // S[B][DP]   = 512
#define WS_C  33280    // c[B]       = 64
#define WS_V  33344    // v[B][DK]   = 131584

// ---------------------------------------------------------------------------
// Kernel A: w[b,f] = gelu(text[b,0,:]@Wt + bt)[f] * Wa[f], stored wT[f][b].
// Also S[b] = column sums of position (g==0 blocks only).
// grid = 256 blocks: (b = blk>>2, g = blk&3); block handles f in [g*128,(g+1)*128).
// Thread t: a = t&31 -> f-quad f0 = g*128+4a; kh = t>>5 -> k in [kh*96,(kh+1)*96).
// ---------------------------------------------------------------------------
__global__ __launch_bounds__(256) void kA(
    const float* __restrict__ pos,   // [B][N][DP]
    const float* __restrict__ text,  // [B][N][DT]
    const float* __restrict__ Wt,    // [DT][DF]
    const float* __restrict__ bt,    // [DF]
    const float* __restrict__ Wa,    // [DF]
    float* __restrict__ wT,          // [DF][B]
    float* __restrict__ S)           // [B][DP]
{
    const int b = blockIdx.x >> 2;
    const int g = blockIdx.x & 3;
    const int t = threadIdx.x;
    const int a = t & 31;
    const int kh = t >> 5;

    __shared__ float tx[DT_];
    __shared__ float4 sred[8][32];
    __shared__ float spos[32][DP_];

    // stage text[b,0,:]
    for (int k = t; k < DT_; k += 256)
        tx[k] = text[(size_t)b * N_ * DT_ + k];

    // position column sums (only g==0 blocks)
    if (g == 0) {
        const int d = t & 7, gi = t >> 3;
        float s = 0.f;
        for (int i = gi; i < N_; i += 32)
            s += pos[(size_t)b * N_ * DP_ + i * DP_ + d];
        spos[gi][d] = s;
    }
    __syncthreads();

    if (g == 0 && t < DP_) {
        float s = 0.f;
        #pragma unroll
        for (int gi = 0; gi < 32; ++gi) s += spos[gi][t];
        S[b * DP_ + t] = s;
    }

    // partial dot over 96 k's, 4 f's per thread (float4 Wt loads)
    const int f0 = g * 128 + 4 * a;
    float4 acc = make_float4(0.f, 0.f, 0.f, 0.f);
    const int kbase = kh * 96;
    for (int j = 0; j < 96; ++j) {
        const int k = kbase + j;
        const float x = tx[k];
        const float4 wv = *(const float4*)(Wt + (size_t)k * DF_ + f0);
        acc.x = fmaf(x, wv.x, acc.x);
        acc.y = fmaf(x, wv.y, acc.y);
        acc.z = fmaf(x, wv.z, acc.z);
        acc.w = fmaf(x, wv.w, acc.w);
    }
    sred[kh][a] = acc;
    __syncthreads();

    if (t < 32) {
        float4 s = sred[0][t];
        #pragma unroll
        for (int h = 1; h < 8; ++h) {
            const float4 p = sred[h][t];
            s.x += p.x; s.y += p.y; s.z += p.z; s.w += p.w;
        }
        const float sv[4] = {s.x, s.y, s.z, s.w};
        #pragma unroll
        for (int cc = 0; cc < 4; ++cc) {
            const int f = g * 128 + 4 * t + cc;
            const float z = sv[cc] + bt[f];
            const float ge = 0.5f * z * (1.f + erff(z * 0.70710678118654752f));
            wT[(size_t)f * B_ + b] = ge * Wa[f];
        }
    }
}

// ---------------------------------------------------------------------------
// Kernel B: v[b,k] = sum_f Wo[k,f]*w[b,f].  Blocks 0..256: 8 k-rows each.
// Block 257: c[b] = sum_f bo[f]*w[b,f] + ba.
// Thread map (main): bq = t&15 (4 b's via float4), rr = (t>>4)&7 (k-row),
//                    hh = t>>7 (f-half of 256).
// ---------------------------------------------------------------------------
__global__ __launch_bounds__(256) void kB(
    const float* __restrict__ Wo,    // [DK][DF]
    const float* __restrict__ bo,    // [DF]
    const float* __restrict__ ba,    // [1]
    const float* __restrict__ wT,    // [DF][B]
    float* __restrict__ v,           // [B][DK]
    float* __restrict__ c)           // [B]
{
    const int t = threadIdx.x;
    __shared__ float  wo[8][DF_ + 4];   // padded rows (bank-conflict-free bcast)
    __shared__ float4 red1[8][16];
    __shared__ float  sbo[DF_];
    __shared__ float4 cred[16][16];

    if (blockIdx.x < 257) {
        const int k0 = blockIdx.x * 8;
        // stage 8 Wo rows (float4)
        for (int idx = t; idx < 8 * 128; idx += 256) {
            const int row = idx >> 7, c4 = idx & 127;
            const float4 x = *(const float4*)(Wo + (size_t)(k0 + row) * DF_ + c4 * 4);
            *(float4*)(&wo[row][c4 * 4]) = x;
        }
        __syncthreads();

        const int bq = t & 15;
        const int rr = (t >> 4) & 7;
        const int hh = t >> 7;
        const float* wrow = wo[rr];
        float4 acc = make_float4(0.f, 0.f, 0.f, 0.f);
        const int fbase = hh * 256;
        for (int j = 0; j < 256; ++j) {
            const int f = fbase + j;
            const float s = wrow[f];
            const float4 wv = *(const float4*)(wT + (size_t)f * B_ + 4 * bq);
            acc.x = fmaf(s, wv.x, acc.x);
            acc.y = fmaf(s, wv.y, acc.y);
            acc.z = fmaf(s, wv.z, acc.z);
            acc.w = fmaf(s, wv.w, acc.w);
        }
        if (hh) red1[rr][bq] = acc;
        __syncthreads();
        if (!hh) {
            const float4 p = red1[rr][bq];
            acc.x += p.x; acc.y += p.y; acc.z += p.z; acc.w += p.w;
            const float av[4] = {acc.x, acc.y, acc.z, acc.w};
            #pragma unroll
            for (int cc = 0; cc < 4; ++cc)
                v[(size_t)(4 * bq + cc) * DK_ + k0 + rr] = av[cc];
        }
    } else {
        // c[b] block
        for (int k = t; k < DF_; k += 256) sbo[k] = bo[k];
        __syncthreads();
        const int bq = t & 15;
        const int fh = t >> 4;           // 16 f-chunks of 32
        float4 acc = make_float4(0.f, 0.f, 0.f, 0.f);
        for (int j = 0; j < 32; ++j) {
            const int f = fh * 32 + j;
            const float s = sbo[f];
            const float4 wv = *(const float4*)(wT + (size_t)f * B_ + 4 * bq);
            acc.x = fmaf(s, wv.x, acc.x);
            acc.y = fmaf(s, wv.y, acc.y);
            acc.z = fmaf(s, wv.z, acc.z);
            acc.w = fmaf(s, wv.w, acc.w);
        }
        cred[fh][bq] = acc;
        __syncthreads();
        if (fh == 0) {
            float4 s = cred[0][bq];
            #pragma unroll
            for (int h = 1; h < 16; ++h) {
                const float4 p = cred[h][bq];
                s.x += p.x; s.y += p.y; s.z += p.z; s.w += p.w;
            }
            const float sv[4] = {s.x, s.y, s.z, s.w};
            #pragma unroll
            for (int cc = 0; cc < 4; ++cc)
                c[4 * bq + cc] = sv[cc] + ba[0];
        }
    }
}

// ---------------------------------------------------------------------------
// Kernel C (bulk, HBM-bound): each wave handles 4 consecutive rows of one b,
// sharing the v1 row load. grid = B*N/16 = 1024 blocks of 256 (4 waves).
// out[b,i] = visual[b,i,:].v1[b] + 257*pos[b,i,:].v2[b] - S[b].v2[b] + c[b]
// ---------------------------------------------------------------------------
__global__ __launch_bounds__(256) void kC(
    const float* __restrict__ visual, // [B][N][DV]
    const float* __restrict__ pos,    // [B][N][DP]
    const float* __restrict__ v,      // [B][DK]
    const float* __restrict__ S,      // [B][DP]
    const float* __restrict__ c,      // [B]
    float* __restrict__ out)          // [B][N]
{
    const int t    = threadIdx.x;
    const int wave = t >> 6;
    const int lane = t & 63;
    const int R0   = blockIdx.x * 16 + wave * 4;  // first of 4 rows
    const int b    = R0 >> 8;
    const int i0   = R0 & 255;

    const float4* vb = (const float4*)(v + (size_t)b * DK_);
    const float4* v0 = (const float4*)(visual + ((size_t)b * N_ + i0) * DV_);

    float a0 = 0.f, a1 = 0.f, a2 = 0.f, a3 = 0.f;
    #pragma unroll
    for (int j = 0; j < 8; ++j) {
        const int idx = lane + 64 * j;
        const float4 wv = vb[idx];
        const float4 x0 = v0[idx];
        const float4 x1 = v0[idx + 512];
        const float4 x2 = v0[idx + 1024];
        const float4 x3 = v0[idx + 1536];
        a0 = fmaf(x0.x, wv.x, a0); a0 = fmaf(x0.y, wv.y, a0);
        a0 = fmaf(x0.z, wv.z, a0); a0 = fmaf(x0.w, wv.w, a0);
        a1 = fmaf(x1.x, wv.x, a1); a1 = fmaf(x1.y, wv.y, a1);
        a1 = fmaf(x1.z, wv.z, a1); a1 = fmaf(x1.w, wv.w, a1);
        a2 = fmaf(x2.x, wv.x, a2); a2 = fmaf(x2.y, wv.y, a2);
        a2 = fmaf(x2.z, wv.z, a2); a2 = fmaf(x2.w, wv.w, a2);
        a3 = fmaf(x3.x, wv.x, a3); a3 = fmaf(x3.y, wv.y, a3);
        a3 = fmaf(x3.z, wv.z, a3); a3 = fmaf(x3.w, wv.w, a3);
    }
    // butterfly all-reduce across wave64
    #pragma unroll
    for (int off = 1; off < 64; off <<= 1) {
        a0 += __shfl_xor(a0, off, 64);
        a1 += __shfl_xor(a1, off, 64);
        a2 += __shfl_xor(a2, off, 64);
        a3 += __shfl_xor(a3, off, 64);
    }

    if (lane < 4) {
        const float accq = (lane == 0) ? a0 : (lane == 1) ? a1 : (lane == 2) ? a2 : a3;
        const int i = i0 + lane;
        const float* v2 = v + (size_t)b * DK_ + DV_;
        const float* pr = pos + ((size_t)b * N_ + i) * DP_;
        const float* Sb = S + b * DP_;
        float pd = 0.f, sd = 0.f;
        #pragma unroll
        for (int d = 0; d < DP_; ++d) {
            pd = fmaf(pr[d], v2[d], pd);
            sd = fmaf(Sb[d], v2[d], sd);
        }
        out[(size_t)b * N_ + i] = accq + 257.f * pd - sd + c[b];
    }
}

// ---------------------------------------------------------------------------
extern "C" void kernel_launch(void* const* d_in, const int* in_sizes, int n_in,
                              void* d_out, int out_size, void* d_ws, size_t ws_size,
                              hipStream_t stream) {
    const float* visual   = (const float*)d_in[0];
    const float* position = (const float*)d_in[1];
    const float* text     = (const float*)d_in[2];
    const float* Wt       = (const float*)d_in[3];
    const float* bt       = (const float*)d_in[4];
    const float* Wo       = (const float*)d_in[5];
    const float* bo       = (const float*)d_in[6];
    const float* Wa       = (const float*)d_in[7];
    const float* ba       = (const float*)d_in[8];
    float* out = (float*)d_out;

    float* ws = (float*)d_ws;
    float* wT = ws + WS_WT;
    float* S  = ws + WS_S;
    float* c  = ws + WS_C;
    float* v  = ws + WS_V;

    kA<<<256, 256, 0, stream>>>(position, text, Wt, bt, Wa, wT, S);
    kB<<<258, 256, 0, stream>>>(Wo, bo, ba, wT, v, c);
    kC<<<(B_ * N_) / 16, 256, 0, stream>>>(visual, position, v, S, c, out);
}

// Round 3
// 49.721 us; speedup vs baseline: 1.5510x; 1.1202x over previous
//
#include <hip/hip_runtime.h>
#include <hip/hip_bf16.h>
#include <math.h>

// Problem constants
#define B_   64
#define N_   256
#define DV_  2048
#define DP_  8
#define DT_  768
#define DF_  512
#define DK_  2056   // DV + DP

// Workspace layout (floats):
#define WS_WT 0        // wT[DF][B]  = 32768
#define WS_S  32768    // S[B][DP]   = 512
#define WS_C  33280    // c[B]       = 64
#define WS_V  33344    // v[B][DK]   = 131584

// ---------------------------------------------------------------------------
// Kernel A: w[b,f] = gelu(text[b,0,:]@Wt + bt)[f] * Wa[f], stored wT[f][b].
// grid = 256 blocks: bq = blk>>4 (b-quad), fg = blk&15 (32-f slice).
// Each block: 4 batches share every Wt float4 load (24 MB total L2 traffic).
// Thread: fq = t&7 (f-quad), kc = t>>3 (24-k chunk).
// S[b] (position column sums) computed by fg==0 blocks.
// ---------------------------------------------------------------------------
__global__ __launch_bounds__(256) void kA(
    const float* __restrict__ pos,   // [B][N][DP]
    const float* __restrict__ text,  // [B][N][DT]
    const float* __restrict__ Wt,    // [DT][DF]
    const float* __restrict__ bt,    // [DF]
    const float* __restrict__ Wa,    // [DF]
    float* __restrict__ wT,          // [DF][B]
    float* __restrict__ S)           // [B][DP]
{
    const int bq = blockIdx.x >> 4;
    const int fg = blockIdx.x & 15;
    const int t  = threadIdx.x;

    __shared__ float  tx[4][DT_];        // 12 KB
    __shared__ float4 sred[4][32][8];    // 16 KB
    __shared__ float  spos[4][8][DP_];   // 1 KB

    // stage text[b,0,:] for the 4 batches
    #pragma unroll
    for (int bb = 0; bb < 4; ++bb)
        for (int k = t; k < DT_; k += 256)
            tx[bb][k] = text[(size_t)(bq * 4 + bb) * N_ * DT_ + k];

    // position column sums (fg==0 blocks only)
    if (fg == 0) {
        const int bb = t >> 6, lane = t & 63;
        const int d = lane & 7, g8 = lane >> 3;
        float s = 0.f;
        for (int i = g8; i < N_; i += 8)
            s += pos[(size_t)(bq * 4 + bb) * N_ * DP_ + i * DP_ + d];
        spos[bb][g8][d] = s;
    }
    __syncthreads();

    if (fg == 0 && t < 32) {
        const int bb = t >> 3, d = t & 7;
        float s = 0.f;
        #pragma unroll
        for (int g = 0; g < 8; ++g) s += spos[bb][g][d];
        S[(bq * 4 + bb) * DP_ + d] = s;
    }

    // main partial dot: 24 k's, 4 f's, 4 b's per thread
    const int fq = t & 7;
    const int kc = t >> 3;
    const int f0 = fg * 32 + fq * 4;
    float4 a0 = make_float4(0.f, 0.f, 0.f, 0.f);
    float4 a1 = a0, a2 = a0, a3 = a0;
    const int kbase = kc * 24;
    #pragma unroll 4
    for (int j = 0; j < 24; ++j) {
        const int k = kbase + j;
        const float4 wv = *(const float4*)(Wt + (size_t)k * DF_ + f0);
        const float x0 = tx[0][k], x1 = tx[1][k], x2 = tx[2][k], x3 = tx[3][k];
        a0.x = fmaf(x0, wv.x, a0.x); a0.y = fmaf(x0, wv.y, a0.y);
        a0.z = fmaf(x0, wv.z, a0.z); a0.w = fmaf(x0, wv.w, a0.w);
        a1.x = fmaf(x1, wv.x, a1.x); a1.y = fmaf(x1, wv.y, a1.y);
        a1.z = fmaf(x1, wv.z, a1.z); a1.w = fmaf(x1, wv.w, a1.w);
        a2.x = fmaf(x2, wv.x, a2.x); a2.y = fmaf(x2, wv.y, a2.y);
        a2.z = fmaf(x2, wv.z, a2.z); a2.w = fmaf(x2, wv.w, a2.w);
        a3.x = fmaf(x3, wv.x, a3.x); a3.y = fmaf(x3, wv.y, a3.y);
        a3.z = fmaf(x3, wv.z, a3.z); a3.w = fmaf(x3, wv.w, a3.w);
    }
    sred[0][kc][fq] = a0;
    sred[1][kc][fq] = a1;
    sred[2][kc][fq] = a2;
    sred[3][kc][fq] = a3;
    __syncthreads();

    if (t < 32) {
        const int bb = t >> 3, fq2 = t & 7;
        float4 s = sred[bb][0][fq2];
        for (int k2 = 1; k2 < 32; ++k2) {
            const float4 p = sred[bb][k2][fq2];
            s.x += p.x; s.y += p.y; s.z += p.z; s.w += p.w;
        }
        const float sv[4] = {s.x, s.y, s.z, s.w};
        const int b = bq * 4 + bb;
        #pragma unroll
        for (int cc = 0; cc < 4; ++cc) {
            const int f = fg * 32 + fq2 * 4 + cc;
            const float z = sv[cc] + bt[f];
            const float ge = 0.5f * z * (1.f + erff(z * 0.70710678118654752f));
            wT[(size_t)f * B_ + b] = ge * Wa[f];
        }
    }
}

// ---------------------------------------------------------------------------
// Kernel B: v[b,k] = sum_f Wo[k,f]*w[b,f].  Blocks 0..513: 4 k-rows each
// (2 blocks/CU, 8 waves/CU). Block 514: c[b] = sum_f bo[f]*w[b,f] + ba.
// Thread map (main): bq = t&15 (4 b's via float4), fg = t>>4 (32-f chunk).
// ---------------------------------------------------------------------------
__global__ __launch_bounds__(256) void kB(
    const float* __restrict__ Wo,    // [DK][DF]
    const float* __restrict__ bo,    // [DF]
    const float* __restrict__ ba,    // [1]
    const float* __restrict__ wT,    // [DF][B]
    float* __restrict__ v,           // [B][DK]
    float* __restrict__ c)           // [B]
{
    const int t = threadIdx.x;
    __shared__ float  wo[4][DF_];       // 8 KB
    __shared__ float4 red[4][16][16];   // 16 KB
    __shared__ float  sbo[DF_];
    __shared__ float4 cred[16][16];

    if (blockIdx.x < 514) {
        const int k0 = blockIdx.x * 4;
        // stage 4 Wo rows (2048 floats = 512 float4)
        {
            const float4* src = (const float4*)(Wo + (size_t)k0 * DF_);
            float4*       dst = (float4*)wo;
            dst[t]       = src[t];
            dst[t + 256] = src[t + 256];
        }
        __syncthreads();

        const int bq = t & 15;
        const int fg = t >> 4;
        float4 acc0 = make_float4(0.f, 0.f, 0.f, 0.f);
        float4 acc1 = acc0, acc2 = acc0, acc3 = acc0;
        const int fbase = fg * 32;
        #pragma unroll 4
        for (int j = 0; j < 32; ++j) {
            const int f = fbase + j;
            const float4 wv = *(const float4*)(wT + (size_t)f * B_ + 4 * bq);
            const float s0 = wo[0][f], s1 = wo[1][f], s2 = wo[2][f], s3 = wo[3][f];
            acc0.x = fmaf(s0, wv.x, acc0.x); acc0.y = fmaf(s0, wv.y, acc0.y);
            acc0.z = fmaf(s0, wv.z, acc0.z); acc0.w = fmaf(s0, wv.w, acc0.w);
            acc1.x = fmaf(s1, wv.x, acc1.x); acc1.y = fmaf(s1, wv.y, acc1.y);
            acc1.z = fmaf(s1, wv.z, acc1.z); acc1.w = fmaf(s1, wv.w, acc1.w);
            acc2.x = fmaf(s2, wv.x, acc2.x); acc2.y = fmaf(s2, wv.y, acc2.y);
            acc2.z = fmaf(s2, wv.z, acc2.z); acc2.w = fmaf(s2, wv.w, acc2.w);
            acc3.x = fmaf(s3, wv.x, acc3.x); acc3.y = fmaf(s3, wv.y, acc3.y);
            acc3.z = fmaf(s3, wv.z, acc3.z); acc3.w = fmaf(s3, wv.w, acc3.w);
        }
        red[0][fg][bq] = acc0;
        red[1][fg][bq] = acc1;
        red[2][fg][bq] = acc2;
        red[3][fg][bq] = acc3;
        __syncthreads();
        if (t < 64) {
            const int r = t >> 4, bq2 = t & 15;
            float4 s = red[r][0][bq2];
            #pragma unroll
            for (int g = 1; g < 16; ++g) {
                const float4 p = red[r][g][bq2];
                s.x += p.x; s.y += p.y; s.z += p.z; s.w += p.w;
            }
            const float sv[4] = {s.x, s.y, s.z, s.w};
            #pragma unroll
            for (int cc = 0; cc < 4; ++cc)
                v[(size_t)(4 * bq2 + cc) * DK_ + k0 + r] = sv[cc];
        }
    } else {
        // c[b] block
        for (int k = t; k < DF_; k += 256) sbo[k] = bo[k];
        __syncthreads();
        const int bq = t & 15;
        const int fh = t >> 4;
        float4 acc = make_float4(0.f, 0.f, 0.f, 0.f);
        for (int j = 0; j < 32; ++j) {
            const int f = fh * 32 + j;
            const float s = sbo[f];
            const float4 wv = *(const float4*)(wT + (size_t)f * B_ + 4 * bq);
            acc.x = fmaf(s, wv.x, acc.x);
            acc.y = fmaf(s, wv.y, acc.y);
            acc.z = fmaf(s, wv.z, acc.z);
            acc.w = fmaf(s, wv.w, acc.w);
        }
        cred[fh][bq] = acc;
        __syncthreads();
        if (fh == 0) {
            float4 s = cred[0][bq];
            #pragma unroll
            for (int h = 1; h < 16; ++h) {
                const float4 p = cred[h][bq];
                s.x += p.x; s.y += p.y; s.z += p.z; s.w += p.w;
            }
            const float sv[4] = {s.x, s.y, s.z, s.w};
            #pragma unroll
            for (int cc = 0; cc < 4; ++cc)
                c[4 * bq + cc] = sv[cc] + ba[0];
        }
    }
}

// ---------------------------------------------------------------------------
// Kernel C (bulk, HBM-bound): 2 rows per wave, 2048 blocks (8 blocks/CU,
// 32 waves/CU) for maximum TLP on the visual stream.
// out[b,i] = visual[b,i,:].v1[b] + 257*pos[b,i,:].v2[b] - S[b].v2[b] + c[b]
// ---------------------------------------------------------------------------
__global__ __launch_bounds__(256) void kC(
    const float* __restrict__ visual, // [B][N][DV]
    const float* __restrict__ pos,    // [B][N][DP]
    const float* __restrict__ v,      // [B][DK]
    const float* __restrict__ S,      // [B][DP]
    const float* __restrict__ c,      // [B]
    float* __restrict__ out)          // [B][N]
{
    const int t    = threadIdx.x;
    const int wave = t >> 6;
    const int lane = t & 63;
    const int R0   = blockIdx.x * 8 + wave * 2;   // first of 2 rows
    const int b    = R0 >> 8;
    const int i0   = R0 & 255;

    const float4* vb = (const float4*)(v + (size_t)b * DK_);
    const float4* v0 = (const float4*)(visual + ((size_t)b * N_ + i0) * DV_);

    float a0 = 0.f, a1 = 0.f;
    #pragma unroll
    for (int j = 0; j < 8; ++j) {
        const int idx = lane + 64 * j;
        const float4 wv = vb[idx];
        const float4 x0 = v0[idx];
        const float4 x1 = v0[idx + 512];
        a0 = fmaf(x0.x, wv.x, a0); a0 = fmaf(x0.y, wv.y, a0);
        a0 = fmaf(x0.z, wv.z, a0); a0 = fmaf(x0.w, wv.w, a0);
        a1 = fmaf(x1.x, wv.x, a1); a1 = fmaf(x1.y, wv.y, a1);
        a1 = fmaf(x1.z, wv.z, a1); a1 = fmaf(x1.w, wv.w, a1);
    }
    #pragma unroll
    for (int off = 1; off < 64; off <<= 1) {
        a0 += __shfl_xor(a0, off, 64);
        a1 += __shfl_xor(a1, off, 64);
    }

    if (lane < 2) {
        const float accq = (lane == 0) ? a0 : a1;
        const int i = i0 + lane;
        const float* v2 = v + (size_t)b * DK_ + DV_;
        const float* pr = pos + ((size_t)b * N_ + i) * DP_;
        const float* Sb = S + b * DP_;
        float pd = 0.f, sd = 0.f;
        #pragma unroll
        for (int d = 0; d < DP_; ++d) {
            pd = fmaf(pr[d], v2[d], pd);
            sd = fmaf(Sb[d], v2[d], sd);
        }
        out[(size_t)b * N_ + i] = accq + 257.f * pd - sd + c[b];
    }
}

// ---------------------------------------------------------------------------
extern "C" void kernel_launch(void* const* d_in, const int* in_sizes, int n_in,
                              void* d_out, int out_size, void* d_ws, size_t ws_size,
                              hipStream_t stream) {
    const float* visual   = (const float*)d_in[0];
    const float* position = (const float*)d_in[1];
    const float* text     = (const float*)d_in[2];
    const float* Wt       = (const float*)d_in[3];
    const float* bt       = (const float*)d_in[4];
    const float* Wo       = (const float*)d_in[5];
    const float* bo       = (const float*)d_in[6];
    const float* Wa       = (const float*)d_in[7];
    const float* ba       = (const float*)d_in[8];
    float* out = (float*)d_out;

    float* ws = (float*)d_ws;
    float* wT = ws + WS_WT;
    float* S  = ws + WS_S;
    float* c  = ws + WS_C;
    float* v  = ws + WS_V;

    kA<<<256, 256, 0, stream>>>(position, text, Wt, bt, Wa, wT, S);
    kB<<<515, 256, 0, stream>>>(Wo, bo, ba, wT, v, c);
    kC<<<2048, 256, 0, stream>>>(visual, position, v, S, c, out);
}